// Round 3
// baseline (72.457 us; speedup 1.0000x reference)
//
#include <hip/hip_runtime.h>
#include <math.h>

#define VOX 64
#define NPOLY 32
#define NEDGE 32
#define NET (NPOLY * NEDGE)   // 1024 edges

// Broadcast lane k's float to the whole wave via v_readlane (VALU crossbar,
// NOT the LDS pipe, no waitcnt). k must be compile-time (loop fully unrolled).
__device__ __forceinline__ float rl(float x, int k) {
    return __int_as_float(__builtin_amdgcn_readlane(__float_as_int(x), k));
}

// block = 1024 threads = 16 waves; grid = B*64 rows = 512 blocks -> 2 blocks/CU
// -> 32 waves/CU = 8 waves/SIMD. Hot loop has ZERO LDS instructions: each lane
// holds one edge's constants; per-edge broadcast is v_readlane.
__global__ __launch_bounds__(1024, 8) void extrusion_kernel(
    const float* __restrict__ polygons,    // (B,32,32,2)
    const float* __restrict__ attributes,  // (B,4)
    const float* __restrict__ validity,    // (B,32)
    float* __restrict__ out)               // (B,64,64,64)
{
    __shared__ float4 ecA[NET];        // x0, ex, ey, inv_norm2
    __shared__ float4 ecB[NET];        // c1 = vy*ey, vy, ix (-1e30 if no y-cross), pad
    __shared__ float  partial[16][VOX];
    __shared__ float  comb[VOX];
    __shared__ int    vIdx[NPOLY];
    __shared__ int    nValidS;

    const int t   = threadIdx.x;
    const int b   = blockIdx.x >> 6;   // batch
    const int row = blockIdx.x & 63;   // y index
    const float py = (float)row * (1.0f / 63.0f);

    // ---- validity compaction: ballot + prefix popcount (first wave) ----
    if (t < 64) {
        bool f = (t < NPOLY) && (validity[b * NPOLY + t] >= 0.5f);
        unsigned long long m = __ballot(f);
        if (f) vIdx[__popcll(m & ((1ull << t) - 1ull))] = t;
        if (t == 0) nValidS = (int)__popcll(m);
    }

    // ---- per-row edge constants: exactly 1 edge per thread ----
    const float2* pb = (const float2*)(polygons + (size_t)b * NET * 2);
    {
        const int e  = t;              // 1024 threads, 1024 edges
        const int n  = e >> 5;
        const int k  = e & 31;
        const int k1 = (k + 1) & 31;
        float2 v0 = pb[n * NEDGE + k];
        float2 v1 = pb[n * NEDGE + k1];
        float ex = v1.x - v0.x;
        float ey = v1.y - v0.y;
        float inv = 1.0f / (ex * ex + ey * ey + 1e-8f);
        float vy  = py - v0.y;
        float c1  = vy * ey;
        bool ycross = ((v0.y <= py) && (v1.y > py)) || ((v1.y <= py) && (v0.y > py));
        float ix = ycross ? (v0.x + ex * (vy / (ey + 1e-8f))) : -1e30f;
        ecA[e] = make_float4(v0.x, ex, ey, inv);
        ecB[e] = make_float4(c1, vy, ix, 0.0f);
    }
    __syncthreads();

    // ---- SDF over compacted valid polygons: ~1 poly per wave ----
    const int g  = t >> 6;             // wave id 0..15 (wave-uniform)
    const int lx = t & 63;             // pixel x
    const int le = t & 31;             // this lane's edge slot
    const float px = (float)lx * (1.0f / 63.0f);
    const int nV = nValidS;

    // acc holds a sign-carrying d^2 key: key = inside ? -d2 : d2.
    // min over keys == min over signed distances (sqrt monotone) -> bit-identical.
    float acc = 1e36f;
    for (int j = g; j < nV; j += 16) {
        const int base = vIdx[j] * NEDGE;
        // lane-distinct one-shot load: lane (l&31) owns edge (l&31)'s constants
        const float4 LA = ecA[base + le];
        const float4 LB = ecB[base + le];

        // 4 independent min-trees + 2 crossing counters (dep chain 32 -> 8)
        float mv0 = 1e30f, mv1 = 1e30f, mv2 = 1e30f, mv3 = 1e30f;
        int   c0 = 0, c1n = 0;
        #pragma unroll
        for (int k = 0; k < NEDGE; k += 2) {
            // broadcast edge k and k+1 constants from their owner lanes (VALU)
            float x00 = rl(LA.x, k),     ex0 = rl(LA.y, k);
            float ey0 = rl(LA.z, k),     in0 = rl(LA.w, k);
            float cc0 = rl(LB.x, k),     vy0 = rl(LB.y, k), ix0 = rl(LB.z, k);
            float x01 = rl(LA.x, k + 1), ex1 = rl(LA.y, k + 1);
            float ey1 = rl(LA.z, k + 1), in1 = rl(LA.w, k + 1);
            float cc1 = rl(LB.x, k + 1), vy1 = rl(LB.y, k + 1), ix1 = rl(LB.z, k + 1);

            float vx0  = px - x00;
            float dot0 = fmaf(vx0, ex0, cc0);
            float tt0  = fminf(fmaxf(dot0 * in0, 0.0f), 1.0f);
            float dx0  = fmaf(-tt0, ex0, vx0);
            float dy0  = fmaf(-tt0, ey0, vy0);
            float d20  = fmaf(dy0, dy0, dx0 * dx0);

            float vx1  = px - x01;
            float dot1 = fmaf(vx1, ex1, cc1);
            float tt1  = fminf(fmaxf(dot1 * in1, 0.0f), 1.0f);
            float dx1  = fmaf(-tt1, ex1, vx1);
            float dy1  = fmaf(-tt1, ey1, vy1);
            float d21  = fmaf(dy1, dy1, dx1 * dx1);

            if ((k & 2) == 0) { mv0 = fminf(mv0, d20); mv1 = fminf(mv1, d21); }
            else              { mv2 = fminf(mv2, d20); mv3 = fminf(mv3, d21); }
            c0  += (ix0 > px) ? 1 : 0;
            c1n += (ix1 > px) ? 1 : 0;
        }
        float mind2 = fminf(fminf(mv0, mv1), fminf(mv2, mv3));
        int cnt = c0 + c1n;
        float key = (cnt & 1) ? -mind2 : mind2;
        acc = fminf(acc, key);
    }
    {
        float ad = sqrtf(fabsf(acc));            // one sqrt per pixel-slot
        partial[g][lx] = (acc < 0.0f) ? -ad : ad;
    }
    __syncthreads();

    // ---- reduce 16 groups -> one sigmoid per pixel (sigmoid monotone) ----
    if (t < VOX) {
        float m = partial[0][t];
        #pragma unroll
        for (int gg = 1; gg < 16; ++gg) m = fminf(m, partial[gg][t]);
        // nV==0 -> m=1e18 -> expf(inf) -> comb=0 (matches reference)
        comb[t] = 1.0f / (1.0f + __expf(100.0f * m));
    }
    __syncthreads();

    // ---- extrusion epilogue: h = clip(floor(att0*64), 1, 64) ----
    float att = attributes[b * 4 + 0];
    int h = max(1, min(64, (int)floorf(att * 64.0f)));

    // 1024 threads: one float4 per thread covers all 64 z-slices of this row
    float4* out4 = (float4*)out;
    const int q = t & 15;              // float4 column
    const int z = t >> 4;              // 0..63
    float4 cv = make_float4(comb[q * 4 + 0], comb[q * 4 + 1],
                            comb[q * 4 + 2], comb[q * 4 + 3]);
    float4 zero = make_float4(0.f, 0.f, 0.f, 0.f);
    size_t base4 = (size_t)b * 65536 + (size_t)row * 16 + q;  // /4 indexing
    out4[base4 + (size_t)z * 1024] = (z < h) ? cv : zero;
}

extern "C" void kernel_launch(void* const* d_in, const int* in_sizes, int n_in,
                              void* d_out, int out_size, void* d_ws, size_t ws_size,
                              hipStream_t stream) {
    const float* polygons   = (const float*)d_in[0];
    const float* attributes = (const float*)d_in[1];
    const float* validity   = (const float*)d_in[2];
    float* out = (float*)d_out;
    const int B = in_sizes[2] / NPOLY;   // 8
    dim3 grid(B * VOX);                  // 512 blocks
    dim3 block(1024);
    extrusion_kernel<<<grid, block, 0, stream>>>(polygons, attributes, validity, out);
}